// Round 3
// baseline (155.265 us; speedup 1.0000x reference)
//
#include <hip/hip_runtime.h>
#include <hip/hip_bf16.h>
#include <stdint.h>

#define Bn 256
#define Sn 512
#define Hn 768
#define Pn 32
#define Kn 3072   // 4*H

typedef __attribute__((ext_vector_type(8))) short short8;
typedef __attribute__((ext_vector_type(4))) float f32x4;

__device__ __forceinline__ unsigned short f2bf(float f) {
    union { float f; unsigned int u; } v;
    v.f = f;
    unsigned int r = v.u + 0x7FFFu + ((v.u >> 16) & 1u);  // RNE
    return (unsigned short)(r >> 16);
}

__device__ __forceinline__ void gload_lds16(const void* src, void* lds) {
    __builtin_amdgcn_global_load_lds(
        (const __attribute__((address_space(1))) unsigned int*)src,
        (__attribute__((address_space(3))) unsigned int*)lds, 16, 0, 0);
}

// Grid barrier: all 256 blocks are co-resident (1 block/CU; 33KB LDS, 256 thr).
// Counters zeroed per call by hipMemsetAsync (graph-legal). Release =
// __threadfence (agent scope, cross-XCD per G16) + device-scope atomicAdd (m20);
// acquire = agent-scope acquire load (invalidates L1/L2 as needed on gfx950).
__device__ __forceinline__ void grid_barrier(unsigned int* cnt, unsigned int nblk) {
    __syncthreads();
    if (threadIdx.x == 0) {
        __threadfence();
        atomicAdd(cnt, 1u);
        while (__hip_atomic_load(cnt, __ATOMIC_ACQUIRE, __HIP_MEMORY_SCOPE_AGENT) < nblk) {
            __builtin_amdgcn_s_sleep(1);
        }
    }
    __syncthreads();
}

struct __align__(16) P1s { unsigned short Al[2][4096]; unsigned short Bl[2][4096]; };

union __align__(16) SharedU {
    struct { int spos[Pn]; float swsum[4]; float sinv; } p0;
    P1s p1;                                   // 32 KB GEMM tiles
    struct { float S[16][16]; float S2[16][16]; } p2;
    float ws4[4];
};

__global__ __launch_bounds__(256) void k_fused(
    const float* __restrict__ pv, const float* __restrict__ mv,
    const int* __restrict__ apos, const float* __restrict__ w1,
    const float* __restrict__ w2, const float* __restrict__ b2,
    const float* __restrict__ gamma, const float* __restrict__ beta,
    unsigned int* __restrict__ bar,
    unsigned short* __restrict__ normb, unsigned short* __restrict__ w1b,
    float* __restrict__ part, float* __restrict__ out1,
    float* __restrict__ scaleF, float* __restrict__ shiftF,
    float* __restrict__ out)
{
    __shared__ SharedU sh;
    const int bid = blockIdx.x;
    const int tid = threadIdx.x;

    // ---------------- Phase 0: pool + L2-norm -> normb; w1 -> bf16 ----------------
    {
        if (tid < Pn) sh.p0.spos[tid] = apos[bid * Pn + tid];
        __syncthreads();

        int cnt = 0;
        #pragma unroll
        for (int p = 0; p < Pn; ++p) cnt += (sh.p0.spos[p] >= 0) ? 1 : 0;
        const float invc = 1.0f / (float)(cnt < 1 ? 1 : cnt);

        float4 pool[2], cls[2];
        float sq = 0.f;
        #pragma unroll
        for (int ti = 0; ti < 2; ++ti) {
            const int t = tid + ti * 256;
            if (t < 384) {
                const float* src  = (t < 192) ? pv : mv;
                const int    col4 = (t < 192) ? t : (t - 192);
                const size_t base = (size_t)bid * ((size_t)Sn * Hn) + (size_t)col4 * 4;
                float4 acc = make_float4(0.f, 0.f, 0.f, 0.f);
                #pragma unroll
                for (int p = 0; p < Pn; ++p) {
                    int q = sh.p0.spos[p];
                    if (q >= 0) {
                        float4 g = *(const float4*)(src + base + (size_t)q * Hn);
                        acc.x += g.x; acc.y += g.y; acc.z += g.z; acc.w += g.w;
                    }
                }
                cls[ti]  = *(const float4*)(src + base);
                pool[ti] = make_float4(acc.x * invc, acc.y * invc, acc.z * invc, acc.w * invc);
                sq += pool[ti].x*pool[ti].x + pool[ti].y*pool[ti].y
                    + pool[ti].z*pool[ti].z + pool[ti].w*pool[ti].w
                    + cls[ti].x*cls[ti].x + cls[ti].y*cls[ti].y
                    + cls[ti].z*cls[ti].z + cls[ti].w*cls[ti].w;
            }
        }
        #pragma unroll
        for (int off = 32; off > 0; off >>= 1) sq += __shfl_down(sq, off);
        if ((tid & 63) == 0) sh.p0.swsum[tid >> 6] = sq;
        __syncthreads();
        if (tid == 0) {
            float t = sh.p0.swsum[0] + sh.p0.swsum[1] + sh.p0.swsum[2] + sh.p0.swsum[3];
            sh.p0.sinv = 1.0f / fmaxf(sqrtf(t), 1e-12f);
        }
        __syncthreads();
        const float s = sh.p0.sinv;

        unsigned short* o = normb + (size_t)bid * Kn;
        #pragma unroll
        for (int ti = 0; ti < 2; ++ti) {
            const int t = tid + ti * 256;
            if (t < 384) {
                const int sect = (t < 192) ? 0 : 2;
                const int col4 = (t < 192) ? t : (t - 192);
                ushort4 u0, u1;
                u0.x = f2bf(pool[ti].x * s); u0.y = f2bf(pool[ti].y * s);
                u0.z = f2bf(pool[ti].z * s); u0.w = f2bf(pool[ti].w * s);
                u1.x = f2bf(cls[ti].x * s);  u1.y = f2bf(cls[ti].y * s);
                u1.z = f2bf(cls[ti].z * s);  u1.w = f2bf(cls[ti].w * s);
                *(ushort4*)(o + sect * Hn + col4 * 4)       = u0;
                *(ushort4*)(o + (sect + 1) * Hn + col4 * 4) = u1;
            }
        }

        // w1 f32 -> bf16, grid-stride (294912 chunks of 8 over 65536 threads)
        for (int c = bid * 256 + tid; c < 294912; c += 65536) {
            const float4 fa = *(const float4*)(w1 + (size_t)c * 8);
            const float4 fb = *(const float4*)(w1 + (size_t)c * 8 + 4);
            ushort4 ua, ub;
            ua.x = f2bf(fa.x); ua.y = f2bf(fa.y); ua.z = f2bf(fa.z); ua.w = f2bf(fa.w);
            ub.x = f2bf(fb.x); ub.y = f2bf(fb.y); ub.z = f2bf(fb.z); ub.w = f2bf(fb.w);
            *(ushort4*)(w1b + (size_t)c * 8)     = ua;
            *(ushort4*)(w1b + (size_t)c * 8 + 4) = ub;
        }
    }
    grid_barrier(bar + 0, 256);

    // ---------------- Phase 1: GEMM partials (192 active blocks) ----------------
    if (bid < 192) {
        const int ks = bid & 3;
        const int mt = (bid >> 2) & 3;
        const int nt = bid >> 4;
        const int m0 = mt * 64, n0 = nt * 64, k0 = ks * 768;

        const int w    = tid >> 6, lane = tid & 63;
        const int r    = lane & 15, g = lane >> 4;
        const int wm   = w >> 1,  wn = w & 1;

        const int id0 = w * 128 + lane;
        const int id1 = id0 + 64;
        const int row0 = id0 >> 3, kg0 = (id0 & 7) ^ (row0 & 7);
        const int row1 = id1 >> 3, kg1 = (id1 & 7) ^ (row1 & 7);

        const unsigned short* a0 = normb + (size_t)(m0 + row0) * Kn + k0 + kg0 * 8;
        const unsigned short* a1 = normb + (size_t)(m0 + row1) * Kn + k0 + kg1 * 8;
        const unsigned short* b0 = w1b   + (size_t)(n0 + row0) * Kn + k0 + kg0 * 8;
        const unsigned short* b1 = w1b   + (size_t)(n0 + row1) * Kn + k0 + kg1 * 8;

        const int dst0 = w * 1024;
        const int dst1 = dst0 + 512;

        f32x4 acc[2][2] = {{{0.f,0.f,0.f,0.f},{0.f,0.f,0.f,0.f}},
                           {{0.f,0.f,0.f,0.f},{0.f,0.f,0.f,0.f}}};

        gload_lds16(a0, &sh.p1.Al[0][dst0]);
        gload_lds16(a1, &sh.p1.Al[0][dst1]);
        gload_lds16(b0, &sh.p1.Bl[0][dst0]);
        gload_lds16(b1, &sh.p1.Bl[0][dst1]);

        int cur = 0;
        for (int s = 0; s < 12; ++s) {
            __syncthreads();
            if (s + 1 < 12) {
                const int ko = (s + 1) * 64;
                gload_lds16(a0 + ko, &sh.p1.Al[cur ^ 1][dst0]);
                gload_lds16(a1 + ko, &sh.p1.Al[cur ^ 1][dst1]);
                gload_lds16(b0 + ko, &sh.p1.Bl[cur ^ 1][dst0]);
                gload_lds16(b1 + ko, &sh.p1.Bl[cur ^ 1][dst1]);
            }
            #pragma unroll
            for (int kq = 0; kq < 2; ++kq) {
                short8 af[2], bf[2];
                #pragma unroll
                for (int ma = 0; ma < 2; ++ma) {
                    const int row = wm * 32 + ma * 16 + r;
                    const int slot = (kq * 4 + g) ^ (row & 7);
                    af[ma] = *(const short8*)&sh.p1.Al[cur][row * 64 + slot * 8];
                }
                #pragma unroll
                for (int nb = 0; nb < 2; ++nb) {
                    const int row = wn * 32 + nb * 16 + r;
                    const int slot = (kq * 4 + g) ^ (row & 7);
                    bf[nb] = *(const short8*)&sh.p1.Bl[cur][row * 64 + slot * 8];
                }
                #pragma unroll
                for (int ma = 0; ma < 2; ++ma)
                    #pragma unroll
                    for (int nb = 0; nb < 2; ++nb)
                        acc[ma][nb] = __builtin_amdgcn_mfma_f32_16x16x32_bf16(
                            af[ma], bf[nb], acc[ma][nb], 0, 0, 0);
            }
            cur ^= 1;
        }

        float* o = part + (size_t)ks * (Bn * Hn);
        #pragma unroll
        for (int ma = 0; ma < 2; ++ma) {
            #pragma unroll
            for (int nb = 0; nb < 2; ++nb) {
                const int orow = m0 + wm * 32 + ma * 16 + g * 4;
                const int ocol = n0 + wn * 32 + nb * 16 + r;
                #pragma unroll
                for (int i = 0; i < 4; ++i)
                    o[(size_t)(orow + i) * Hn + ocol] = acc[ma][nb][i];
            }
        }
    }
    grid_barrier(bar + 16, 256);

    // ---------------- Phase 2: fold K-partials + BN stats (48 active) ----------------
    if (bid < 48) {
        const int fo = tid & 15, rg = tid >> 4;
        const int f = bid * 16 + fo;
        const float* p0 = part + f;
        const float* p1 = p0 + Bn * Hn;
        const float* p2 = p1 + Bn * Hn;
        const float* p3 = p2 + Bn * Hn;

        float s = 0.f, s2 = 0.f;
        #pragma unroll
        for (int i = 0; i < 16; ++i) {
            const size_t off = (size_t)(rg * 16 + i) * Hn;
            const float y = p0[off] + p1[off] + p2[off] + p3[off];
            out1[off + f] = y;
            s += y; s2 += y * y;
        }
        sh.p2.S[rg][fo] = s; sh.p2.S2[rg][fo] = s2;
        __syncthreads();
        if (tid < 16) {
            const int ff = bid * 16 + tid;
            float ts = 0.f, ts2 = 0.f;
            #pragma unroll
            for (int i = 0; i < 16; ++i) { ts += sh.p2.S[i][tid]; ts2 += sh.p2.S2[i][tid]; }
            const float mean = ts * (1.0f / 256.0f);
            const float var  = fmaxf(ts2 * (1.0f / 256.0f) - mean * mean, 0.0f);
            const float sc   = gamma[ff] / sqrtf(var + 1e-5f);
            scaleF[ff] = sc;
            shiftF[ff] = beta[ff] - mean * sc;
        }
    }
    grid_barrier(bar + 32, 256);

    // ---------------- Phase 3: BN-apply + ReLU + fc2 dot (all blocks) ----------------
    {
        float acc = 0.f;
        #pragma unroll
        for (int j = 0; j < 3; ++j) {
            const int h = tid + j * 256;
            const float x = out1[(size_t)bid * Hn + h];
            const float v = fmaxf(x * scaleF[h] + shiftF[h], 0.f);
            acc += v * w2[h];
        }
        #pragma unroll
        for (int off = 32; off > 0; off >>= 1) acc += __shfl_down(acc, off);
        if ((tid & 63) == 0) sh.ws4[tid >> 6] = acc;
        __syncthreads();
        if (tid == 0) out[bid] = sh.ws4[0] + sh.ws4[1] + sh.ws4[2] + sh.ws4[3] + b2[0];
    }
}

extern "C" void kernel_launch(void* const* d_in, const int* in_sizes, int n_in,
                              void* d_out, int out_size, void* d_ws, size_t ws_size,
                              hipStream_t stream)
{
    const float* pv    = (const float*)d_in[0];
    const float* mv    = (const float*)d_in[1];
    const int*   apos  = (const int*)d_in[2];
    const float* w1    = (const float*)d_in[3];
    const float* w2    = (const float*)d_in[5];
    const float* b2    = (const float*)d_in[6];
    const float* gamma = (const float*)d_in[7];
    const float* beta  = (const float*)d_in[8];
    float* out = (float*)d_out;

    char* ws = (char*)d_ws;
    unsigned int*   bar    = (unsigned int*)ws;                       // 256 B (3 counters, padded)
    unsigned short* normb  = (unsigned short*)(ws + 256);             // 1,572,864 B
    unsigned short* w1b    = (unsigned short*)(ws + 256 + 1572864);   // 4,718,592 B
    float*          part   = (float*)(ws + 256 + 1572864 + 4718592);  // 3,145,728 B
    float*          out1   = (float*)(ws + 256 + 1572864 + 4718592 + 3145728);   // 786,432 B
    float*          scaleF = (float*)(ws + 256 + 1572864 + 4718592 + 3145728 + 786432);
    float*          shiftF = (float*)(ws + 256 + 1572864 + 4718592 + 3145728 + 786432 + 4096);

    hipMemsetAsync(bar, 0, 256, stream);   // zero barrier counters (graph-legal memset node)
    hipLaunchKernelGGL(k_fused, dim3(256), dim3(256), 0, stream,
                       pv, mv, apos, w1, w2, b2, gamma, beta,
                       bar, normb, w1b, part, out1, scaleF, shiftF, out);
}

// Round 4
// 38.422 us; speedup vs baseline: 4.0410x; 4.0410x over previous
//
#include <hip/hip_runtime.h>
#include <hip/hip_bf16.h>
#include <stdint.h>

#define Bn 256
#define Sn 512
#define Hn 768
#define Pn 32
#define Kn 3072   // 4*H

typedef __attribute__((ext_vector_type(8))) short short8;
typedef __attribute__((ext_vector_type(4))) float f32x4;

__device__ __forceinline__ unsigned short f2bf(float f) {
    union { float f; unsigned int u; } v;
    v.f = f;
    unsigned int r = v.u + 0x7FFFu + ((v.u >> 16) & 1u);  // RNE
    return (unsigned short)(r >> 16);
}

__device__ __forceinline__ void gload_lds16(const void* src, void* lds) {
    __builtin_amdgcn_global_load_lds(
        (const __attribute__((address_space(1))) unsigned int*)src,
        (__attribute__((address_space(3))) unsigned int*)lds, 16, 0, 0);
}

// K1: masked-mean pool + cls + concat + L2-normalize -> bf16 normb[256][3072]
//     + tail: convert fc1_w (f32) -> w1b (bf16), grid-stride.
// 768 threads/block (12 waves/CU for gather latency hiding), float2/lane.
__global__ __launch_bounds__(768) void k_pool_norm(
    const float* __restrict__ pv, const float* __restrict__ mv,
    const int* __restrict__ apos, unsigned short* __restrict__ normb,
    const float* __restrict__ w1, unsigned short* __restrict__ w1b)
{
    const int b   = blockIdx.x;
    const int tid = threadIdx.x;

    __shared__ int   spos[Pn];
    __shared__ float swsum[12];
    __shared__ float sinv;

    if (tid < Pn) spos[tid] = apos[b * Pn + tid];
    __syncthreads();

    int cnt = 0;
    #pragma unroll
    for (int p = 0; p < Pn; ++p) cnt += (spos[p] >= 0) ? 1 : 0;
    const float invc = 1.0f / (float)(cnt < 1 ? 1 : cnt);

    const float* src  = (tid < 384) ? pv : mv;
    const int    col2 = (tid < 384) ? tid : (tid - 384);   // float2 index 0..383
    const size_t base = (size_t)b * ((size_t)Sn * Hn) + (size_t)col2 * 2;

    float2 acc = make_float2(0.f, 0.f);
    #pragma unroll
    for (int p = 0; p < Pn; ++p) {
        int q = spos[p];            // uniform across block
        if (q >= 0) {
            float2 g = *(const float2*)(src + base + (size_t)q * Hn);
            acc.x += g.x; acc.y += g.y;
        }
    }
    float2 cls  = *(const float2*)(src + base);   // row 0
    float2 pool = make_float2(acc.x * invc, acc.y * invc);

    float sq = pool.x*pool.x + pool.y*pool.y + cls.x*cls.x + cls.y*cls.y;
    #pragma unroll
    for (int off = 32; off > 0; off >>= 1) sq += __shfl_down(sq, off);
    if ((tid & 63) == 0) swsum[tid >> 6] = sq;
    __syncthreads();
    if (tid == 0) {
        float t = 0.f;
        #pragma unroll
        for (int i = 0; i < 12; ++i) t += swsum[i];
        sinv = 1.0f / fmaxf(sqrtf(t), 1e-12f);
    }
    __syncthreads();
    const float s = sinv;

    const int sect = (tid < 384) ? 0 : 2;
    unsigned short* o = normb + (size_t)b * Kn;
    ushort2 u0, u1;
    u0.x = f2bf(pool.x * s); u0.y = f2bf(pool.y * s);
    u1.x = f2bf(cls.x  * s); u1.y = f2bf(cls.y  * s);
    *(ushort2*)(o + sect * Hn + col2 * 2)       = u0;
    *(ushort2*)(o + (sect + 1) * Hn + col2 * 2) = u1;

    // --- tail: fc1_w f32 -> bf16 (294912 chunks of 8 over 196608 threads) ---
    const int gtid = b * 768 + tid;
    for (int c = gtid; c < 294912; c += 196608) {
        const float4 fa = *(const float4*)(w1 + (size_t)c * 8);
        const float4 fb = *(const float4*)(w1 + (size_t)c * 8 + 4);
        ushort4 ua, ub;
        ua.x = f2bf(fa.x); ua.y = f2bf(fa.y); ua.z = f2bf(fa.z); ua.w = f2bf(fa.w);
        ub.x = f2bf(fb.x); ub.y = f2bf(fb.y); ub.z = f2bf(fb.z); ub.w = f2bf(fb.w);
        *(ushort4*)(w1b + (size_t)c * 8)     = ua;
        *(ushort4*)(w1b + (size_t)c * 8 + 4) = ub;
    }
}

// K2: partial[ks][256][768] = normb @ w1b^T over K-chunk ks.
// 64x64 block tile, BK=64, 4 waves (2x2), each wave 32x32 via 2x2x2 mfma_16x16x32.
// LDS: XOR-swizzled (slot = kg ^ (row&7)); staged with global_load_lds width-16:
// linear LDS dest + inverse-swizzled global source (G21 both-sides rule).
#define NSTEP 12   // 768 / 64
__global__ __launch_bounds__(256) void k_gemm(
    const unsigned short* __restrict__ A,   // normb [256][3072]
    const unsigned short* __restrict__ Bw,  // w1b   [768][3072]
    float* __restrict__ part)               // [4][256][768]
{
    __shared__ __align__(16) unsigned short Al[2][64 * 64];
    __shared__ __align__(16) unsigned short Bl[2][64 * 64];

    const int bid = blockIdx.x;
    const int ks = bid & 3;
    const int mt = (bid >> 2) & 3;
    const int nt = bid >> 4;                 // 0..11
    const int m0 = mt * 64, n0 = nt * 64, k0 = ks * 768;

    const int tid  = threadIdx.x;
    const int w    = tid >> 6, lane = tid & 63;
    const int r    = lane & 15, g = lane >> 4;
    const int wm   = w >> 1,  wn = w & 1;

    const int id0 = w * 128 + lane;
    const int id1 = id0 + 64;
    const int row0 = id0 >> 3, kg0 = (id0 & 7) ^ (row0 & 7);
    const int row1 = id1 >> 3, kg1 = (id1 & 7) ^ (row1 & 7);

    const unsigned short* a0 = A  + (size_t)(m0 + row0) * Kn + k0 + kg0 * 8;
    const unsigned short* a1 = A  + (size_t)(m0 + row1) * Kn + k0 + kg1 * 8;
    const unsigned short* b0 = Bw + (size_t)(n0 + row0) * Kn + k0 + kg0 * 8;
    const unsigned short* b1 = Bw + (size_t)(n0 + row1) * Kn + k0 + kg1 * 8;

    const int dst0 = w * 1024;
    const int dst1 = dst0 + 512;

    f32x4 acc[2][2] = {{{0.f,0.f,0.f,0.f},{0.f,0.f,0.f,0.f}},
                       {{0.f,0.f,0.f,0.f},{0.f,0.f,0.f,0.f}}};

    gload_lds16(a0, &Al[0][dst0]);
    gload_lds16(a1, &Al[0][dst1]);
    gload_lds16(b0, &Bl[0][dst0]);
    gload_lds16(b1, &Bl[0][dst1]);

    int cur = 0;
    for (int s = 0; s < NSTEP; ++s) {
        __syncthreads();
        if (s + 1 < NSTEP) {
            const int ko = (s + 1) * 64;
            gload_lds16(a0 + ko, &Al[cur ^ 1][dst0]);
            gload_lds16(a1 + ko, &Al[cur ^ 1][dst1]);
            gload_lds16(b0 + ko, &Bl[cur ^ 1][dst0]);
            gload_lds16(b1 + ko, &Bl[cur ^ 1][dst1]);
        }
        #pragma unroll
        for (int kq = 0; kq < 2; ++kq) {
            short8 af[2], bf[2];
            #pragma unroll
            for (int ma = 0; ma < 2; ++ma) {
                const int row = wm * 32 + ma * 16 + r;
                const int slot = (kq * 4 + g) ^ (row & 7);
                af[ma] = *(const short8*)&Al[cur][row * 64 + slot * 8];
            }
            #pragma unroll
            for (int nb = 0; nb < 2; ++nb) {
                const int row = wn * 32 + nb * 16 + r;
                const int slot = (kq * 4 + g) ^ (row & 7);
                bf[nb] = *(const short8*)&Bl[cur][row * 64 + slot * 8];
            }
            #pragma unroll
            for (int ma = 0; ma < 2; ++ma)
                #pragma unroll
                for (int nb = 0; nb < 2; ++nb)
                    acc[ma][nb] = __builtin_amdgcn_mfma_f32_16x16x32_bf16(
                        af[ma], bf[nb], acc[ma][nb], 0, 0, 0);
        }
        cur ^= 1;
    }

    float* o = part + (size_t)ks * (Bn * Hn);
    #pragma unroll
    for (int ma = 0; ma < 2; ++ma) {
        #pragma unroll
        for (int nb = 0; nb < 2; ++nb) {
            const int orow = m0 + wm * 32 + ma * 16 + g * 4;
            const int ocol = n0 + wn * 32 + nb * 16 + r;
            #pragma unroll
            for (int i = 0; i < 4; ++i)
                o[(size_t)(orow + i) * Hn + ocol] = acc[ma][nb][i];
        }
    }
}

// K3: fold 4 K-partials -> out1 (fc1 bias cancels through BN), BN stats -> scale/shift.
__global__ __launch_bounds__(256) void k_bnfold(
    const float* __restrict__ part, const float* __restrict__ gamma,
    const float* __restrict__ beta, float* __restrict__ out1,
    float* __restrict__ scaleF, float* __restrict__ shiftF)
{
    const int blk = blockIdx.x;
    const int fo = threadIdx.x & 15, rg = threadIdx.x >> 4;
    const int f = blk * 16 + fo;
    const float* p0 = part + f;
    const float* p1 = p0 + Bn * Hn;
    const float* p2 = p1 + Bn * Hn;
    const float* p3 = p2 + Bn * Hn;

    float s = 0.f, s2 = 0.f;
    #pragma unroll
    for (int i = 0; i < 16; ++i) {
        const size_t off = (size_t)(rg * 16 + i) * Hn;
        const float y = p0[off] + p1[off] + p2[off] + p3[off];
        out1[off + f] = y;
        s += y; s2 += y * y;
    }
    __shared__ float S[16][16], S2[16][16];
    S[rg][fo] = s; S2[rg][fo] = s2;
    __syncthreads();
    if (threadIdx.x < 16) {
        const int ff = blk * 16 + threadIdx.x;
        float ts = 0.f, ts2 = 0.f;
        #pragma unroll
        for (int i = 0; i < 16; ++i) { ts += S[i][threadIdx.x]; ts2 += S2[i][threadIdx.x]; }
        const float mean = ts * (1.0f / 256.0f);
        const float var  = fmaxf(ts2 * (1.0f / 256.0f) - mean * mean, 0.0f);
        const float sc   = gamma[ff] / sqrtf(var + 1e-5f);
        scaleF[ff] = sc;
        shiftF[ff] = beta[ff] - mean * sc;
    }
}

// K4: per-row BN-apply + ReLU + fc2 dot -> out[256].
__global__ __launch_bounds__(256) void k_fc2(
    const float* __restrict__ out1, const float* __restrict__ scaleF,
    const float* __restrict__ shiftF, const float* __restrict__ w2,
    const float* __restrict__ b2, float* __restrict__ out)
{
    const int b = blockIdx.x, tid = threadIdx.x;
    float acc = 0.f;
    #pragma unroll
    for (int j = 0; j < 3; ++j) {
        const int h = tid + j * 256;
        const float x = out1[(size_t)b * Hn + h];
        const float v = fmaxf(x * scaleF[h] + shiftF[h], 0.f);
        acc += v * w2[h];
    }
    #pragma unroll
    for (int off = 32; off > 0; off >>= 1) acc += __shfl_down(acc, off);
    __shared__ float ws4[4];
    if ((tid & 63) == 0) ws4[tid >> 6] = acc;
    __syncthreads();
    if (tid == 0) out[b] = ws4[0] + ws4[1] + ws4[2] + ws4[3] + b2[0];
}

extern "C" void kernel_launch(void* const* d_in, const int* in_sizes, int n_in,
                              void* d_out, int out_size, void* d_ws, size_t ws_size,
                              hipStream_t stream)
{
    const float* pv    = (const float*)d_in[0];
    const float* mv    = (const float*)d_in[1];
    const int*   apos  = (const int*)d_in[2];
    const float* w1    = (const float*)d_in[3];
    const float* w2    = (const float*)d_in[5];
    const float* b2    = (const float*)d_in[6];
    const float* gamma = (const float*)d_in[7];
    const float* beta  = (const float*)d_in[8];
    float* out = (float*)d_out;

    char* ws = (char*)d_ws;
    unsigned short* normb  = (unsigned short*)ws;                    // 1,572,864 B
    unsigned short* w1b    = (unsigned short*)(ws + 1572864);        // 4,718,592 B
    float*          part   = (float*)(ws + 1572864 + 4718592);      // 3,145,728 B
    float*          out1   = (float*)(ws + 1572864 + 4718592 + 3145728);      // 786,432 B
    float*          scaleF = (float*)(ws + 1572864 + 4718592 + 3145728 + 786432);
    float*          shiftF = (float*)(ws + 1572864 + 4718592 + 3145728 + 786432 + 4096);

    hipLaunchKernelGGL(k_pool_norm, dim3(Bn),  dim3(768), 0, stream, pv, mv, apos, normb, w1, w1b);
    hipLaunchKernelGGL(k_gemm,      dim3(192), dim3(256), 0, stream, normb, w1b, part);
    hipLaunchKernelGGL(k_bnfold,    dim3(48),  dim3(256), 0, stream, part, gamma, beta, out1, scaleF, shiftF);
    hipLaunchKernelGGL(k_fc2,       dim3(Bn),  dim3(256), 0, stream, out1, scaleF, shiftF, w2, b2, out);
}

// Round 5
// 37.185 us; speedup vs baseline: 4.1755x; 1.0333x over previous
//
#include <hip/hip_runtime.h>
#include <hip/hip_bf16.h>
#include <stdint.h>

#define Bn 256
#define Sn 512
#define Hn 768
#define Pn 32
#define Kn 3072   // 4*H

typedef __attribute__((ext_vector_type(8))) short short8;
typedef __attribute__((ext_vector_type(4))) float f32x4;

__device__ __forceinline__ unsigned short f2bf(float f) {
    union { float f; unsigned int u; } v;
    v.f = f;
    unsigned int r = v.u + 0x7FFFu + ((v.u >> 16) & 1u);  // RNE
    return (unsigned short)(r >> 16);
}

__device__ __forceinline__ void gload_lds16(const void* src, void* lds) {
    __builtin_amdgcn_global_load_lds(
        (const __attribute__((address_space(1))) unsigned int*)src,
        (__attribute__((address_space(3))) unsigned int*)lds, 16, 0, 0);
}

// K1: masked-mean pool + cls + concat + L2-normalize -> bf16 normb[256][3072]
//     + tail: convert fc1_w (f32) -> w1b (bf16), grid-stride. (R2-proven form)
__global__ __launch_bounds__(384) void k_pool_norm(
    const float* __restrict__ pv, const float* __restrict__ mv,
    const int* __restrict__ apos, unsigned short* __restrict__ normb,
    const float* __restrict__ w1, unsigned short* __restrict__ w1b)
{
    const int b   = blockIdx.x;
    const int tid = threadIdx.x;

    __shared__ int   spos[Pn];
    __shared__ float swsum[6];
    __shared__ float sinv;

    if (tid < Pn) spos[tid] = apos[b * Pn + tid];
    __syncthreads();

    int cnt = 0;
    #pragma unroll
    for (int p = 0; p < Pn; ++p) cnt += (spos[p] >= 0) ? 1 : 0;
    const float invc = 1.0f / (float)(cnt < 1 ? 1 : cnt);

    const float* src  = (tid < 192) ? pv : mv;
    const int    col4 = (tid < 192) ? tid : (tid - 192);
    const size_t base = (size_t)b * ((size_t)Sn * Hn) + (size_t)col4 * 4;

    float4 acc = make_float4(0.f, 0.f, 0.f, 0.f);
    #pragma unroll
    for (int p = 0; p < Pn; ++p) {
        int q = spos[p];            // uniform across block -> no divergence
        if (q >= 0) {
            float4 g = *(const float4*)(src + base + (size_t)q * Hn);
            acc.x += g.x; acc.y += g.y; acc.z += g.z; acc.w += g.w;
        }
    }
    float4 cls  = *(const float4*)(src + base);   // row 0
    float4 pool = make_float4(acc.x * invc, acc.y * invc, acc.z * invc, acc.w * invc);

    float sq = pool.x*pool.x + pool.y*pool.y + pool.z*pool.z + pool.w*pool.w
             + cls.x*cls.x  + cls.y*cls.y  + cls.z*cls.z  + cls.w*cls.w;
    #pragma unroll
    for (int off = 32; off > 0; off >>= 1) sq += __shfl_down(sq, off);
    if ((tid & 63) == 0) swsum[tid >> 6] = sq;
    __syncthreads();
    if (tid == 0) {
        float t = swsum[0] + swsum[1] + swsum[2] + swsum[3] + swsum[4] + swsum[5];
        sinv = 1.0f / fmaxf(sqrtf(t), 1e-12f);
    }
    __syncthreads();
    const float s = sinv;

    const int sect = (tid < 192) ? 0 : 2;
    unsigned short* o = normb + (size_t)b * Kn;
    ushort4 u0, u1;
    u0.x = f2bf(pool.x * s); u0.y = f2bf(pool.y * s); u0.z = f2bf(pool.z * s); u0.w = f2bf(pool.w * s);
    u1.x = f2bf(cls.x  * s); u1.y = f2bf(cls.y  * s); u1.z = f2bf(cls.z  * s); u1.w = f2bf(cls.w  * s);
    *(ushort4*)(o + sect * Hn + col4 * 4)       = u0;
    *(ushort4*)(o + (sect + 1) * Hn + col4 * 4) = u1;

    // tail: fc1_w f32 -> bf16 (294912 chunks of 8 over 98304 threads)
    const int gtid = b * 384 + tid;
    for (int c = gtid; c < 294912; c += 98304) {
        const float4 fa = *(const float4*)(w1 + (size_t)c * 8);
        const float4 fb = *(const float4*)(w1 + (size_t)c * 8 + 4);
        ushort4 ua, ub;
        ua.x = f2bf(fa.x); ua.y = f2bf(fa.y); ua.z = f2bf(fa.z); ua.w = f2bf(fa.w);
        ub.x = f2bf(fb.x); ub.y = f2bf(fb.y); ub.z = f2bf(fb.z); ub.w = f2bf(fb.w);
        *(ushort4*)(w1b + (size_t)c * 8)     = ua;
        *(ushort4*)(w1b + (size_t)c * 8 + 4) = ub;
    }
}

// K2: partial[ks][256][768] = normb @ w1b^T over K-chunk ks (R2-proven form).
// Tail: block 0 initializes out[0..255] = b2[0] (consumed by K_C's atomicAdds
// in the NEXT kernel -> ordering guaranteed by the stream).
#define NSTEP 12   // 768 / 64
__global__ __launch_bounds__(256) void k_gemm(
    const unsigned short* __restrict__ A,   // normb [256][3072]
    const unsigned short* __restrict__ Bw,  // w1b   [768][3072]
    float* __restrict__ part,               // [4][256][768]
    const float* __restrict__ b2, float* __restrict__ out)
{
    __shared__ __align__(16) unsigned short Al[2][64 * 64];
    __shared__ __align__(16) unsigned short Bl[2][64 * 64];

    const int bid = blockIdx.x;
    const int ks = bid & 3;
    const int mt = (bid >> 2) & 3;
    const int nt = bid >> 4;                 // 0..11
    const int m0 = mt * 64, n0 = nt * 64, k0 = ks * 768;

    const int tid  = threadIdx.x;
    const int w    = tid >> 6, lane = tid & 63;
    const int r    = lane & 15, g = lane >> 4;
    const int wm   = w >> 1,  wn = w & 1;

    if (bid == 0) out[tid] = b2[0];   // init for K_C atomic accumulation

    const int id0 = w * 128 + lane;
    const int id1 = id0 + 64;
    const int row0 = id0 >> 3, kg0 = (id0 & 7) ^ (row0 & 7);
    const int row1 = id1 >> 3, kg1 = (id1 & 7) ^ (row1 & 7);

    const unsigned short* a0 = A  + (size_t)(m0 + row0) * Kn + k0 + kg0 * 8;
    const unsigned short* a1 = A  + (size_t)(m0 + row1) * Kn + k0 + kg1 * 8;
    const unsigned short* b0 = Bw + (size_t)(n0 + row0) * Kn + k0 + kg0 * 8;
    const unsigned short* b1 = Bw + (size_t)(n0 + row1) * Kn + k0 + kg1 * 8;

    const int dst0 = w * 1024;
    const int dst1 = dst0 + 512;

    f32x4 acc[2][2] = {{{0.f,0.f,0.f,0.f},{0.f,0.f,0.f,0.f}},
                       {{0.f,0.f,0.f,0.f},{0.f,0.f,0.f,0.f}}};

    gload_lds16(a0, &Al[0][dst0]);
    gload_lds16(a1, &Al[0][dst1]);
    gload_lds16(b0, &Bl[0][dst0]);
    gload_lds16(b1, &Bl[0][dst1]);

    int cur = 0;
    for (int s = 0; s < NSTEP; ++s) {
        __syncthreads();
        if (s + 1 < NSTEP) {
            const int ko = (s + 1) * 64;
            gload_lds16(a0 + ko, &Al[cur ^ 1][dst0]);
            gload_lds16(a1 + ko, &Al[cur ^ 1][dst1]);
            gload_lds16(b0 + ko, &Bl[cur ^ 1][dst0]);
            gload_lds16(b1 + ko, &Bl[cur ^ 1][dst1]);
        }
        #pragma unroll
        for (int kq = 0; kq < 2; ++kq) {
            short8 af[2], bf[2];
            #pragma unroll
            for (int ma = 0; ma < 2; ++ma) {
                const int row = wm * 32 + ma * 16 + r;
                const int slot = (kq * 4 + g) ^ (row & 7);
                af[ma] = *(const short8*)&Al[cur][row * 64 + slot * 8];
            }
            #pragma unroll
            for (int nb = 0; nb < 2; ++nb) {
                const int row = wn * 32 + nb * 16 + r;
                const int slot = (kq * 4 + g) ^ (row & 7);
                bf[nb] = *(const short8*)&Bl[cur][row * 64 + slot * 8];
            }
            #pragma unroll
            for (int ma = 0; ma < 2; ++ma)
                #pragma unroll
                for (int nb = 0; nb < 2; ++nb)
                    acc[ma][nb] = __builtin_amdgcn_mfma_f32_16x16x32_bf16(
                        af[ma], bf[nb], acc[ma][nb], 0, 0, 0);
        }
        cur ^= 1;
    }

    float* o = part + (size_t)ks * (Bn * Hn);
    #pragma unroll
    for (int ma = 0; ma < 2; ++ma) {
        #pragma unroll
        for (int nb = 0; nb < 2; ++nb) {
            const int orow = m0 + wm * 32 + ma * 16 + g * 4;
            const int ocol = n0 + wn * 32 + nb * 16 + r;
            #pragma unroll
            for (int i = 0; i < 4; ++i)
                o[(size_t)(orow + i) * Hn + ocol] = acc[ma][nb][i];
        }
    }
}

// K_C: fused fold + BN stats + BN-apply + ReLU + fc2.
// 48 blocks x 256 threads; block owns 16 features (all 256 rows).
// Per-row partial dot with w2 over the block's 16 features -> atomicAdd(out[row]).
// fc1 bias cancels exactly through BN and is dropped.
__global__ __launch_bounds__(256) void k_bnfc2(
    const float* __restrict__ part, const float* __restrict__ gamma,
    const float* __restrict__ beta, const float* __restrict__ w2,
    float* __restrict__ out)
{
    const int blk = blockIdx.x;
    const int fo = threadIdx.x & 15, rg = threadIdx.x >> 4;
    const int f = blk * 16 + fo;
    const float* p0 = part + f;
    const float* p1 = p0 + Bn * Hn;
    const float* p2 = p1 + Bn * Hn;
    const float* p3 = p2 + Bn * Hn;

    float y[16];
    float s = 0.f, s2 = 0.f;
    #pragma unroll
    for (int i = 0; i < 16; ++i) {
        const size_t off = (size_t)(rg * 16 + i) * Hn;
        const float v = p0[off] + p1[off] + p2[off] + p3[off];
        y[i] = v;
        s += v; s2 += v * v;
    }

    __shared__ float S[16][16], S2[16][16];
    __shared__ float sc_s[16], sh_s[16], w2_s[16];
    S[rg][fo] = s; S2[rg][fo] = s2;
    __syncthreads();
    if (threadIdx.x < 16) {
        const int ff = blk * 16 + threadIdx.x;
        float ts = 0.f, ts2 = 0.f;
        #pragma unroll
        for (int i = 0; i < 16; ++i) { ts += S[i][threadIdx.x]; ts2 += S2[i][threadIdx.x]; }
        const float mean = ts * (1.0f / 256.0f);
        const float var  = fmaxf(ts2 * (1.0f / 256.0f) - mean * mean, 0.0f);
        const float sc   = gamma[ff] / sqrtf(var + 1e-5f);
        sc_s[threadIdx.x] = sc;
        sh_s[threadIdx.x] = beta[ff] - mean * sc;
        w2_s[threadIdx.x] = w2[ff];
    }
    __syncthreads();

    const float sc = sc_s[fo], sh = sh_s[fo], wv = w2_s[fo];
    __shared__ float R[256][17];   // +1 pad: column reads below stride 17 -> no bank conflict
    #pragma unroll
    for (int i = 0; i < 16; ++i)
        R[rg * 16 + i][fo] = fmaxf(y[i] * sc + sh, 0.f) * wv;
    __syncthreads();

    // per-row sum over the 16 features, one thread per row
    float rs = 0.f;
    #pragma unroll
    for (int j = 0; j < 16; ++j) rs += R[threadIdx.x][j];
    atomicAdd(out + threadIdx.x, rs);
}

extern "C" void kernel_launch(void* const* d_in, const int* in_sizes, int n_in,
                              void* d_out, int out_size, void* d_ws, size_t ws_size,
                              hipStream_t stream)
{
    const float* pv    = (const float*)d_in[0];
    const float* mv    = (const float*)d_in[1];
    const int*   apos  = (const int*)d_in[2];
    const float* w1    = (const float*)d_in[3];
    const float* w2    = (const float*)d_in[5];
    const float* b2    = (const float*)d_in[6];
    const float* gamma = (const float*)d_in[7];
    const float* beta  = (const float*)d_in[8];
    float* out = (float*)d_out;

    char* ws = (char*)d_ws;
    unsigned short* normb = (unsigned short*)ws;                  // 1,572,864 B
    unsigned short* w1b   = (unsigned short*)(ws + 1572864);      // 4,718,592 B
    float*          part  = (float*)(ws + 1572864 + 4718592);     // 3,145,728 B

    hipLaunchKernelGGL(k_pool_norm, dim3(Bn),  dim3(384), 0, stream, pv, mv, apos, normb, w1, w1b);
    hipLaunchKernelGGL(k_gemm,      dim3(192), dim3(256), 0, stream, normb, w1b, part, b2, (float*)d_out);
    hipLaunchKernelGGL(k_bnfc2,     dim3(48),  dim3(256), 0, stream, part, gamma, beta, w2, (float*)d_out);
}

// Round 6
// 26.747 us; speedup vs baseline: 5.8049x; 1.3902x over previous
//
#include <hip/hip_runtime.h>
#include <hip/hip_bf16.h>
#include <stdint.h>

#define Bn 256
#define Sn 512
#define Hn 768
#define Pn 32
#define Kn 3072   // 4*H

typedef __attribute__((ext_vector_type(8))) short short8;
typedef __attribute__((ext_vector_type(4))) float f32x4;

__device__ __forceinline__ unsigned short f2bf(float f) {
    union { float f; unsigned int u; } v;
    v.f = f;
    unsigned int r = v.u + 0x7FFFu + ((v.u >> 16) & 1u);  // RNE
    return (unsigned short)(r >> 16);
}

__device__ __forceinline__ void gload_lds16(const void* src, void* lds) {
    __builtin_amdgcn_global_load_lds(
        (const __attribute__((address_space(1))) unsigned int*)src,
        (__attribute__((address_space(3))) unsigned int*)lds, 16, 0, 0);
}

// K1: masked-mean pool + cls + concat + L2-normalize -> bf16 normb[256][3072].
// Gather is compacted (ballot) and padded to a multiple of 8 with row-0 entries
// (compensated by subtracting extra*cls) so all loads are UNCONDITIONAL and the
// compiler can keep 8 in flight instead of serializing per-branch.
__global__ __launch_bounds__(384) void k_pool_norm(
    const float* __restrict__ pv, const float* __restrict__ mv,
    const int* __restrict__ apos, unsigned short* __restrict__ normb)
{
    const int b   = blockIdx.x;
    const int tid = threadIdx.x;

    __shared__ int   cpos[Pn + 8];
    __shared__ int   scnt, spad;
    __shared__ float swsum[6];
    __shared__ float sinv;

    if (tid < 64) {   // first wave: parallel compaction
        int q = (tid < Pn) ? apos[b * Pn + tid] : -1;
        const unsigned long long m = __ballot(q >= 0);
        const int c = __popcll(m);
        if (q >= 0) {
            const int rank = __popcll(m & ((1ull << tid) - 1ull));
            cpos[rank] = q;
        }
        const int pad = (8 - (c & 7)) & 7;
        if (tid < pad) cpos[c + tid] = 0;     // pad with row 0 (compensated later)
        if (tid == 0) { scnt = c; spad = c + pad; }
    }
    __syncthreads();
    const int cnt = scnt, padded = spad;
    const float invc = 1.0f / (float)(cnt < 1 ? 1 : cnt);

    const float* src  = (tid < 192) ? pv : mv;
    const int    col4 = (tid < 192) ? tid : (tid - 192);
    const size_t base = (size_t)b * ((size_t)Sn * Hn) + (size_t)col4 * 4;

    float4 acc = make_float4(0.f, 0.f, 0.f, 0.f);
    for (int p0 = 0; p0 < padded; p0 += 8) {
        float4 g[8];
        #pragma unroll
        for (int j = 0; j < 8; ++j)
            g[j] = *(const float4*)(src + base + (size_t)cpos[p0 + j] * Hn);
        #pragma unroll
        for (int j = 0; j < 8; ++j) {
            acc.x += g[j].x; acc.y += g[j].y; acc.z += g[j].z; acc.w += g[j].w;
        }
    }
    float4 cls = *(const float4*)(src + base);   // row 0
    const float e = (float)(padded - cnt);       // remove the pad contributions
    acc.x -= e * cls.x; acc.y -= e * cls.y; acc.z -= e * cls.z; acc.w -= e * cls.w;
    float4 pool = make_float4(acc.x * invc, acc.y * invc, acc.z * invc, acc.w * invc);

    float sq = pool.x*pool.x + pool.y*pool.y + pool.z*pool.z + pool.w*pool.w
             + cls.x*cls.x  + cls.y*cls.y  + cls.z*cls.z  + cls.w*cls.w;
    #pragma unroll
    for (int off = 32; off > 0; off >>= 1) sq += __shfl_down(sq, off);
    if ((tid & 63) == 0) swsum[tid >> 6] = sq;
    __syncthreads();
    if (tid == 0) {
        float t = swsum[0] + swsum[1] + swsum[2] + swsum[3] + swsum[4] + swsum[5];
        sinv = 1.0f / fmaxf(sqrtf(t), 1e-12f);
    }
    __syncthreads();
    const float s = sinv;

    const int sect = (tid < 192) ? 0 : 2;
    unsigned short* o = normb + (size_t)b * Kn;
    ushort4 u0, u1;
    u0.x = f2bf(pool.x * s); u0.y = f2bf(pool.y * s); u0.z = f2bf(pool.z * s); u0.w = f2bf(pool.w * s);
    u1.x = f2bf(cls.x  * s); u1.y = f2bf(cls.y  * s); u1.z = f2bf(cls.z  * s); u1.w = f2bf(cls.w  * s);
    *(ushort4*)(o + sect * Hn + col4 * 4)       = u0;
    *(ushort4*)(o + (sect + 1) * Hn + col4 * 4) = u1;
}

// K2: partial[ks][256][768] = normb @ w1^T over K-chunk ks (KSPLIT=8, 6 steps).
// A staged via global_load_lds (bf16); B staged from f32 w1 with in-register
// f32->bf16 cvt + swizzled ds_write_b128 (T14 split: loads issued before the
// MFMA section, converted/written after). 384 blocks -> up to 2 blocks/CU for
// inter-block latency overlap (__launch_bounds__(256,2)).
#define KSPLIT 8
#define NS 6   // (3072/KSPLIT)/64
__global__ __launch_bounds__(256, 2) void k_gemm(
    const unsigned short* __restrict__ A,   // normb [256][3072]
    const float* __restrict__ W,            // fc1_w [768][3072] f32
    float* __restrict__ part,               // [8][256][768]
    const float* __restrict__ b2, float* __restrict__ out)
{
    __shared__ __align__(16) unsigned short Al[2][64 * 64];
    __shared__ __align__(16) unsigned short Bl[2][64 * 64];

    const int bid = blockIdx.x;
    const int ks = bid & 7;
    const int mt = (bid >> 3) & 3;
    const int nt = bid >> 5;                 // 0..11
    const int m0 = mt * 64, n0 = nt * 64, k0 = ks * 384;

    const int tid  = threadIdx.x;
    const int w    = tid >> 6, lane = tid & 63;
    const int r    = lane & 15, g = lane >> 4;
    const int wm   = w >> 1,  wn = w & 1;

    if (bid == 0) out[tid] = b2[0];   // init for K_C atomic accumulation

    const int id0 = w * 128 + lane;
    const int id1 = id0 + 64;
    const int row0 = id0 >> 3, kg0 = (id0 & 7) ^ (row0 & 7);
    const int row1 = id1 >> 3, kg1 = (id1 & 7) ^ (row1 & 7);

    const unsigned short* a0 = A + (size_t)(m0 + row0) * Kn + k0 + kg0 * 8;
    const unsigned short* a1 = A + (size_t)(m0 + row1) * Kn + k0 + kg1 * 8;
    const float*          w0 = W + (size_t)(n0 + row0) * Kn + k0 + kg0 * 8;
    const float*          w1p = W + (size_t)(n0 + row1) * Kn + k0 + kg1 * 8;

    const int abase = w * 1024;        // wave-uniform LDS base for gload (elements)
    const int dst0  = id0 * 8;         // per-lane ds_write targets (elements)
    const int dst1  = id1 * 8;

    f32x4 acc[2][2] = {{{0.f,0.f,0.f,0.f},{0.f,0.f,0.f,0.f}},
                       {{0.f,0.f,0.f,0.f},{0.f,0.f,0.f,0.f}}};

    // prologue: stage step 0 into buf 0
    gload_lds16(a0, &Al[0][abase]);
    gload_lds16(a1, &Al[0][abase + 512]);
    {
        const float4 fa = *(const float4*)(w0);
        const float4 fb = *(const float4*)(w0 + 4);
        const float4 fc = *(const float4*)(w1p);
        const float4 fd = *(const float4*)(w1p + 4);
        short8 c0, c1;
        c0[0]=(short)f2bf(fa.x); c0[1]=(short)f2bf(fa.y); c0[2]=(short)f2bf(fa.z); c0[3]=(short)f2bf(fa.w);
        c0[4]=(short)f2bf(fb.x); c0[5]=(short)f2bf(fb.y); c0[6]=(short)f2bf(fb.z); c0[7]=(short)f2bf(fb.w);
        c1[0]=(short)f2bf(fc.x); c1[1]=(short)f2bf(fc.y); c1[2]=(short)f2bf(fc.z); c1[3]=(short)f2bf(fc.w);
        c1[4]=(short)f2bf(fd.x); c1[5]=(short)f2bf(fd.y); c1[6]=(short)f2bf(fd.z); c1[7]=(short)f2bf(fd.w);
        *(short8*)&Bl[0][dst0] = c0;
        *(short8*)&Bl[0][dst1] = c1;
    }

    int cur = 0;
    for (int s = 0; s < NS; ++s) {
        __syncthreads();   // buf[cur] staged (vmcnt+lgkm drained by barrier)
        float4 na, nb, nc, nd;
        if (s + 1 < NS) {
            const int ko = (s + 1) * 64;
            gload_lds16(a0 + ko, &Al[cur ^ 1][abase]);
            gload_lds16(a1 + ko, &Al[cur ^ 1][abase + 512]);
            na = *(const float4*)(w0 + ko);
            nb = *(const float4*)(w0 + ko + 4);
            nc = *(const float4*)(w1p + ko);
            nd = *(const float4*)(w1p + ko + 4);
        }
        #pragma unroll
        for (int kq = 0; kq < 2; ++kq) {
            short8 af[2], bf[2];
            #pragma unroll
            for (int ma = 0; ma < 2; ++ma) {
                const int row = wm * 32 + ma * 16 + r;
                const int slot = (kq * 4 + g) ^ (row & 7);
                af[ma] = *(const short8*)&Al[cur][row * 64 + slot * 8];
            }
            #pragma unroll
            for (int nbx = 0; nbx < 2; ++nbx) {
                const int row = wn * 32 + nbx * 16 + r;
                const int slot = (kq * 4 + g) ^ (row & 7);
                bf[nbx] = *(const short8*)&Bl[cur][row * 64 + slot * 8];
            }
            #pragma unroll
            for (int ma = 0; ma < 2; ++ma)
                #pragma unroll
                for (int nbx = 0; nbx < 2; ++nbx)
                    acc[ma][nbx] = __builtin_amdgcn_mfma_f32_16x16x32_bf16(
                        af[ma], bf[nbx], acc[ma][nbx], 0, 0, 0);
        }
        if (s + 1 < NS) {   // convert + write AFTER compute (loads arrived by now)
            short8 c0, c1;
            c0[0]=(short)f2bf(na.x); c0[1]=(short)f2bf(na.y); c0[2]=(short)f2bf(na.z); c0[3]=(short)f2bf(na.w);
            c0[4]=(short)f2bf(nb.x); c0[5]=(short)f2bf(nb.y); c0[6]=(short)f2bf(nb.z); c0[7]=(short)f2bf(nb.w);
            c1[0]=(short)f2bf(nc.x); c1[1]=(short)f2bf(nc.y); c1[2]=(short)f2bf(nc.z); c1[3]=(short)f2bf(nc.w);
            c1[4]=(short)f2bf(nd.x); c1[5]=(short)f2bf(nd.y); c1[6]=(short)f2bf(nd.z); c1[7]=(short)f2bf(nd.w);
            *(short8*)&Bl[cur ^ 1][dst0] = c0;
            *(short8*)&Bl[cur ^ 1][dst1] = c1;
        }
        cur ^= 1;
    }

    float* o = part + (size_t)ks * (Bn * Hn);
    #pragma unroll
    for (int ma = 0; ma < 2; ++ma) {
        #pragma unroll
        for (int nbx = 0; nbx < 2; ++nbx) {
            const int orow = m0 + wm * 32 + ma * 16 + g * 4;
            const int ocol = n0 + wn * 32 + nbx * 16 + r;
            #pragma unroll
            for (int i = 0; i < 4; ++i)
                o[(size_t)(orow + i) * Hn + ocol] = acc[ma][nbx][i];
        }
    }
}

// K_C: fused fold(8 partials) + BN stats + BN-apply + ReLU + fc2.
// 48 blocks x 256; block owns 16 features; per-row partial dots -> atomicAdd(out).
// fc1 bias cancels exactly through BN and is dropped.
__global__ __launch_bounds__(256) void k_bnfc2(
    const float* __restrict__ part, const float* __restrict__ gamma,
    const float* __restrict__ beta, const float* __restrict__ w2,
    float* __restrict__ out)
{
    const int blk = blockIdx.x;
    const int fo = threadIdx.x & 15, rg = threadIdx.x >> 4;
    const int f = blk * 16 + fo;
    const float* p = part + f;

    float y[16];
    float s = 0.f, s2 = 0.f;
    #pragma unroll
    for (int i = 0; i < 16; ++i) {
        const size_t off = (size_t)(rg * 16 + i) * Hn;
        float v = 0.f;
        #pragma unroll
        for (int j = 0; j < KSPLIT; ++j) v += p[(size_t)j * (Bn * Hn) + off];
        y[i] = v;
        s += v; s2 += v * v;
    }

    __shared__ float S[16][16], S2[16][16];
    __shared__ float sc_s[16], sh_s[16], w2_s[16];
    S[rg][fo] = s; S2[rg][fo] = s2;
    __syncthreads();
    if (threadIdx.x < 16) {
        const int ff = blk * 16 + threadIdx.x;
        float ts = 0.f, ts2 = 0.f;
        #pragma unroll
        for (int i = 0; i < 16; ++i) { ts += S[i][threadIdx.x]; ts2 += S2[i][threadIdx.x]; }
        const float mean = ts * (1.0f / 256.0f);
        const float var  = fmaxf(ts2 * (1.0f / 256.0f) - mean * mean, 0.0f);
        const float sc   = gamma[ff] / sqrtf(var + 1e-5f);
        sc_s[threadIdx.x] = sc;
        sh_s[threadIdx.x] = beta[ff] - mean * sc;
        w2_s[threadIdx.x] = w2[ff];
    }
    __syncthreads();

    const float sc = sc_s[fo], sh = sh_s[fo], wv = w2_s[fo];
    __shared__ float R[256][17];
    #pragma unroll
    for (int i = 0; i < 16; ++i)
        R[rg * 16 + i][fo] = fmaxf(y[i] * sc + sh, 0.f) * wv;
    __syncthreads();

    float rs = 0.f;
    #pragma unroll
    for (int j = 0; j < 16; ++j) rs += R[threadIdx.x][j];
    atomicAdd(out + threadIdx.x, rs);
}

extern "C" void kernel_launch(void* const* d_in, const int* in_sizes, int n_in,
                              void* d_out, int out_size, void* d_ws, size_t ws_size,
                              hipStream_t stream)
{
    const float* pv    = (const float*)d_in[0];
    const float* mv    = (const float*)d_in[1];
    const int*   apos  = (const int*)d_in[2];
    const float* w1    = (const float*)d_in[3];
    const float* w2    = (const float*)d_in[5];
    const float* b2    = (const float*)d_in[6];
    const float* gamma = (const float*)d_in[7];
    const float* beta  = (const float*)d_in[8];

    char* ws = (char*)d_ws;
    unsigned short* normb = (unsigned short*)ws;               // 1,572,864 B
    float*          part  = (float*)(ws + 1572864);            // 6,291,456 B

    hipLaunchKernelGGL(k_pool_norm, dim3(Bn),  dim3(384), 0, stream, pv, mv, apos, normb);
    hipLaunchKernelGGL(k_gemm,      dim3(384), dim3(256), 0, stream, normb, w1, part, b2, (float*)d_out);
    hipLaunchKernelGGL(k_bnfc2,     dim3(48),  dim3(256), 0, stream, part, gamma, beta, w2, (float*)d_out);
}